// Round 9
// baseline (147.915 us; speedup 1.0000x reference)
//
#include <hip/hip_runtime.h>
#include <hip/hip_bf16.h>

#define HEADS 4
#define ODIM 64
#define HD 256          // HEADS*ODIM
#define NEG_SLOPE 0.2f
#define SPLITS 8        // KR = 512
#define MI 256          // i-tile per aggregate block

typedef __attribute__((ext_vector_type(8))) short bf16x8;
typedef __attribute__((ext_vector_type(4))) float floatx4;
typedef __attribute__((ext_vector_type(2))) float floatx2;

// ============ pack x and W -> bf16 hi/lo MFMA fragments (one launch) ============
__global__ __launch_bounds__(256) void pack_xw(const float* __restrict__ x,
                                               const float* __restrict__ W,
                                               __hip_bfloat16* __restrict__ xh,
                                               __hip_bfloat16* __restrict__ xl,
                                               __hip_bfloat16* __restrict__ wh,
                                               __hip_bfloat16* __restrict__ wl,
                                               int K, int nxb) {
    const int b = blockIdx.x;
    const int Kc = K >> 5;
    if (b < nxb) {
        const int g = b * 256 + threadIdx.x;
        const int lane = g & 63, frag = g >> 6;
        const int kc = frag % Kc, mc = frag / Kc;
        const int l16 = lane & 15, q = lane >> 4;
        const float* src = x + (size_t)(mc * 16 + l16) * K + kc * 32 + q * 8;
        const float4 v0 = *(const float4*)src;
        const float4 v1 = *(const float4*)(src + 4);
        const float vv[8] = {v0.x, v0.y, v0.z, v0.w, v1.x, v1.y, v1.z, v1.w};
        union { __hip_bfloat16 b[8]; bf16x8 v; } H, L;
        #pragma unroll
        for (int p = 0; p < 8; ++p) {
            H.b[p] = __float2bfloat16(vv[p]);
            L.b[p] = __float2bfloat16(vv[p] - __bfloat162float(H.b[p]));
        }
        *(bf16x8*)&xh[(size_t)frag * 512 + lane * 8] = H.v;
        *(bf16x8*)&xl[(size_t)frag * 512 + lane * 8] = L.v;
    } else {
        const int g = (b - nxb) * 256 + threadIdx.x;
        const int lane = g & 63, frag = g >> 6;
        const int kc = frag % Kc, nc = frag / Kc;
        const int l16 = lane & 15, q = lane >> 4;
        union { __hip_bfloat16 b[8]; bf16x8 v; } H, L;
        #pragma unroll
        for (int p = 0; p < 8; ++p) {
            const float w = W[(size_t)(kc * 32 + q * 8 + p) * HD + nc * 16 + l16];
            H.b[p] = __float2bfloat16(w);
            L.b[p] = __float2bfloat16(w - __bfloat162float(H.b[p]));
        }
        *(bf16x8*)&wh[(size_t)frag * 512 + lane * 8] = H.v;
        *(bf16x8*)&wl[(size_t)frag * 512 + lane * 8] = L.v;
    }
}

// ============ compress adj -> bit matrix (pure streaming) ============
// block: row = blockIdx.y, j-range [blockIdx.x*1024, +1024); wave w covers 256 j via 4 ballots.
__global__ __launch_bounds__(256) void compress_adj(const int* __restrict__ adj,
                                                    unsigned int* __restrict__ bits, int n) {
    const int wave = threadIdx.x >> 6, lane = threadIdx.x & 63;
    const int i = blockIdx.y;
    const int j0 = blockIdx.x * 1024 + wave * 256;
    unsigned long long m[4];
    #pragma unroll
    for (int k = 0; k < 4; ++k)
        m[k] = __ballot(adj[(size_t)i * n + j0 + k * 64 + lane] > 0);
    if (lane == 0) {
        uint4 u, v;
        u.x = (unsigned)m[0]; u.y = (unsigned)(m[0] >> 32);
        u.z = (unsigned)m[1]; u.w = (unsigned)(m[1] >> 32);
        v.x = (unsigned)m[2]; v.y = (unsigned)(m[2] >> 32);
        v.z = (unsigned)m[3]; v.w = (unsigned)(m[3] >> 32);
        *(uint4*)&bits[(size_t)i * (n >> 5) + (j0 >> 5)] = u;
        *(uint4*)&bits[(size_t)i * (n >> 5) + (j0 >> 5) + 4] = v;
    }
}

// ============ fused GEMM: h = x@W (hi/lo bf16 MFMA) + exp epilogue + B-frag pack of h ============
__global__ __launch_bounds__(128) void gemm_fused(
    const __hip_bfloat16* __restrict__ xh, const __hip_bfloat16* __restrict__ xl,
    const __hip_bfloat16* __restrict__ wh, const __hip_bfloat16* __restrict__ wl,
    const float* __restrict__ att, float2* __restrict__ esrc, float2* __restrict__ edst,
    __hip_bfloat16* __restrict__ hbB, int n, int K) {

    __shared__ __hip_bfloat16 T[64][40];

    const int tid = threadIdx.x, wave = tid >> 6, lane = tid & 63;
    const int q = lane >> 4, l16 = lane & 15;
    const int m0 = blockIdx.x * 32;
    const int head = blockIdx.y;
    const int Kc = K >> 5;
    const int mc = (m0 >> 4) + wave;

    floatx4 acc[4] = {{0.f,0.f,0.f,0.f},{0.f,0.f,0.f,0.f},{0.f,0.f,0.f,0.f},{0.f,0.f,0.f,0.f}};

    const __hip_bfloat16* Axh = xh + (size_t)mc * Kc * 512 + lane * 8;
    const __hip_bfloat16* Axl = xl + (size_t)mc * Kc * 512 + lane * 8;
    const __hip_bfloat16* Bwh = wh + lane * 8;
    const __hip_bfloat16* Bwl = wl + lane * 8;
    #pragma unroll 2
    for (int kc = 0; kc < Kc; ++kc) {
        const bf16x8 ah = *(const bf16x8*)(Axh + (size_t)kc * 512);
        const bf16x8 al = *(const bf16x8*)(Axl + (size_t)kc * 512);
        bf16x8 bh[4], bl[4];
        #pragma unroll
        for (int nt = 0; nt < 4; ++nt) {
            const size_t fo = (size_t)((head * 4 + nt) * Kc + kc) * 512;
            bh[nt] = *(const bf16x8*)(Bwh + fo);
            bl[nt] = *(const bf16x8*)(Bwl + fo);
        }
        #pragma unroll
        for (int nt = 0; nt < 4; ++nt)
            acc[nt] = __builtin_amdgcn_mfma_f32_16x16x32_bf16(ah, bh[nt], acc[nt], 0, 0, 0);
        #pragma unroll
        for (int nt = 0; nt < 4; ++nt)
            acc[nt] = __builtin_amdgcn_mfma_f32_16x16x32_bf16(ah, bl[nt], acc[nt], 0, 0, 0);
        #pragma unroll
        for (int nt = 0; nt < 4; ++nt)
            acc[nt] = __builtin_amdgcn_mfma_f32_16x16x32_bf16(al, bh[nt], acc[nt], 0, 0, 0);
    }

    // ---- exp epilogue ----
    float as_v[4], ad_v[4];
    #pragma unroll
    for (int nt = 0; nt < 4; ++nt) {
        as_v[nt] = att[head * 2 * ODIM + nt * 16 + l16];
        ad_v[nt] = att[head * 2 * ODIM + ODIM + nt * 16 + l16];
    }
    #pragma unroll
    for (int r = 0; r < 4; ++r) {
        float ps = 0.f, pd = 0.f;
        #pragma unroll
        for (int nt = 0; nt < 4; ++nt) {
            ps = fmaf(acc[nt][r], as_v[nt], ps);
            pd = fmaf(acc[nt][r], ad_v[nt], pd);
        }
        #pragma unroll
        for (int m = 1; m <= 8; m <<= 1) {
            ps += __shfl_xor(ps, m, 64);
            pd += __shfl_xor(pd, m, 64);
        }
        if (l16 == 0) {
            const int i = m0 + wave * 16 + q * 4 + r;
            esrc[head * n + i] = make_float2(__expf(ps), __expf(NEG_SLOPE * ps));
            edst[head * n + i] = make_float2(__expf(pd), __expf(NEG_SLOPE * pd));
        }
    }

    // ---- write h tile transposed to LDS as bf16 ----
    #pragma unroll
    for (int nt = 0; nt < 4; ++nt) {
        union { __hip_bfloat16 b[4]; uint2 u; } pk;
        #pragma unroll
        for (int r = 0; r < 4; ++r) pk.b[r] = __float2bfloat16(acc[nt][r]);
        *(uint2*)&T[nt * 16 + l16][wave * 16 + q * 4] = pk.u;
    }
    __syncthreads();

    // ---- emit packed B-frags of h ----
    #pragma unroll
    for (int ffi = 0; ffi < 2; ++ffi) {
        const int f = wave + ffi * 2;   // nt
        const bf16x8 v = *(const bf16x8*)&T[f * 16 + l16][q * 8];
        const size_t frag = ((size_t)head * (n >> 5) + (m0 >> 5)) * 4 + f;
        *(bf16x8*)&hbB[frag * 512 + lane * 8] = v;
    }
}

// ============ aggregate v9: i-tile 256, one head/block, LDS-staged everything ============
// grid (n/256, HEADS, SPLITS) = 512 blocks (2/CU). Block: 4 waves, wave = 64 rows (mt=4).
// hbB traffic cut 8x vs v8 (268 MB -> 32 MB): B-frags staged per 64-j chunk into dbuf LDS.
__global__ __launch_bounds__(256, 2) void aggregate(
    const unsigned int* __restrict__ bits, const float2* __restrict__ esrc,
    const float2* __restrict__ edst, const __hip_bfloat16* __restrict__ hbB,
    float* __restrict__ outsp, float* __restrict__ densp, int n, int KR) {

    __shared__ unsigned int bitsL[MI][17];        // [row][jword], 16 jwords (KR=512) + pad
    __shared__ float2 edL[512];                   // this head's dst-exp slice
    __shared__ __hip_bfloat16 hbL[2][8][512];     // dbuf: 8 frags (2 steps) per chunk

    const int tid = threadIdx.x;
    const int wave = tid >> 6, lane = tid & 63;
    const int q = lane >> 4, l16 = lane & 15;
    const int i0 = blockIdx.x * MI;
    const int head = blockIdx.y;
    const int K0 = blockIdx.z * KR;
    const int nw = n >> 5;

    // ---- stage bits rectangle (MI rows x 16 dwords; 64 B per 16 lanes, coalesced-ish) ----
    {
        const int dw = tid & 15, rb = tid >> 4;
        #pragma unroll
        for (int rr = 0; rr < 16; ++rr) {
            const int row = rr * 16 + rb;
            bitsL[row][dw] = bits[(size_t)(i0 + row) * nw + (K0 >> 5) + dw];
        }
    }
    // ---- stage dst-exp slice (coalesced float2) ----
    for (int t = tid; t < KR; t += 256)
        edL[t] = edst[(size_t)head * n + K0 + t];

    // ---- src-side exps for this lane's 4 rows ----
    floatx2 es12[4];
    #pragma unroll
    for (int mt = 0; mt < 4; ++mt) {
        const float2 e = esrc[head * n + i0 + wave * 64 + mt * 16 + l16];
        es12[mt][0] = e.x; es12[mt][1] = e.y;
    }

    // ones-column B-frag for MFMA-based denominator
    union { short s[8]; bf16x8 v; } bones;
    #pragma unroll
    for (int p = 0; p < 8; ++p) bones.s[p] = (l16 == 0) ? (short)0x3F80 : (short)0;

    floatx4 acc[4][4];
    floatx4 accd[4];
    #pragma unroll
    for (int mt = 0; mt < 4; ++mt) {
        accd[mt] = (floatx4){0.f, 0.f, 0.f, 0.f};
        #pragma unroll
        for (int nt = 0; nt < 4; ++nt) acc[mt][nt] = (floatx4){0.f, 0.f, 0.f, 0.f};
    }

    // hbB source for this (head, K-range): chunks of 8 KB, contiguous
    const __hip_bfloat16* hbsrc = hbB + ((size_t)head * (n >> 5) + (K0 >> 5)) * 4 * 512;

    uint4 stg0, stg1;
    auto loadChunk = [&](int c) {        // global -> regs (stays in flight during compute)
        const uint4* src = (const uint4*)(hbsrc + (size_t)c * 4096);
        stg0 = src[tid * 2];
        stg1 = src[tid * 2 + 1];
    };
    auto writeChunk = [&](int buf) {     // regs -> LDS
        uint4* dst = (uint4*)&hbL[buf][0][0];
        dst[tid * 2] = stg0;
        dst[tid * 2 + 1] = stg1;
    };

    auto computeStep = [&](int buf, int sIn, int s) {
        // adjacency bytes for this lane's 4 rows (LDS, 16-lane distinct banks, q-broadcast)
        unsigned int bm[4];
        #pragma unroll
        for (int mt = 0; mt < 4; ++mt)
            bm[mt] = (bitsL[wave * 64 + mt * 16 + l16][s] >> (q * 8)) & 0xFFu;
        // dst exps for this lane's 8 j's
        const float4* ep = (const float4*)&edL[s * 32 + q * 8];
        const float4 e01 = ep[0], e23 = ep[1], e45 = ep[2], e67 = ep[3];
        floatx2 ed[8];
        ed[0][0]=e01.x; ed[0][1]=e01.y;  ed[1][0]=e01.z; ed[1][1]=e01.w;
        ed[2][0]=e23.x; ed[2][1]=e23.y;  ed[3][0]=e23.z; ed[3][1]=e23.w;
        ed[4][0]=e45.x; ed[4][1]=e45.y;  ed[5][0]=e45.z; ed[5][1]=e45.w;
        ed[6][0]=e67.x; ed[6][1]=e67.y;  ed[7][0]=e67.z; ed[7][1]=e67.w;
        // B-frags from LDS
        bf16x8 bfr[4];
        #pragma unroll
        for (int nt = 0; nt < 4; ++nt)
            bfr[nt] = *(const bf16x8*)&hbL[buf][sIn * 4 + nt][lane * 8];
        #pragma unroll
        for (int mt = 0; mt < 4; ++mt) {
            union { unsigned int u[4]; bf16x8 v; } af;
            #pragma unroll
            for (int p = 0; p < 4; ++p) {
                const floatx2 pa = es12[mt] * ed[2 * p];
                const floatx2 pb = es12[mt] * ed[2 * p + 1];
                const float wa = fmaxf(pa[0], pa[1]);   // leaky-relu in exp domain
                const float wb = fmaxf(pb[0], pb[1]);
                const unsigned int mm = ((bm[mt] >> (2 * p)) & 1u) * 0xFFFFu
                                      | ((bm[mt] >> (2 * p + 1)) & 1u) * 0xFFFF0000u;
                af.u[p] = __builtin_amdgcn_perm(__float_as_uint(wb), __float_as_uint(wa),
                                                0x07060302u) & mm;
            }
            #pragma unroll
            for (int nt = 0; nt < 4; ++nt)
                acc[mt][nt] = __builtin_amdgcn_mfma_f32_16x16x32_bf16(af.v, bfr[nt], acc[mt][nt], 0, 0, 0);
            accd[mt] = __builtin_amdgcn_mfma_f32_16x16x32_bf16(af.v, bones.v, accd[mt], 0, 0, 0);
        }
    };

    // ---- prologue: chunk 0 -> buf 0 (also covers the bits/edL staging barrier) ----
    loadChunk(0);
    writeChunk(0);
    __syncthreads();

    const int NCH = KR >> 6;   // 8 chunks of 64 j (2 steps)
    int cur = 0;
    for (int c = 0; c < NCH; ++c) {
        if (c + 1 < NCH) loadChunk(c + 1);      // in flight across the two computeSteps
        computeStep(cur, 0, c * 2);
        computeStep(cur, 1, c * 2 + 1);
        if (c + 1 < NCH) {
            writeChunk(cur ^ 1);
            __syncthreads();                    // one barrier per 64-j chunk
            cur ^= 1;
        }
    }

    // ---- epilogue: disjoint per-split writes ----
    const size_t sOut = (size_t)blockIdx.z * n * HD;
    #pragma unroll
    for (int mt = 0; mt < 4; ++mt)
        #pragma unroll
        for (int nt = 0; nt < 4; ++nt)
            #pragma unroll
            for (int r = 0; r < 4; ++r)
                outsp[sOut + (size_t)(i0 + wave * 64 + mt * 16 + q * 4 + r) * HD
                      + head * ODIM + nt * 16 + l16] = acc[mt][nt][r];
    if (l16 == 0) {
        #pragma unroll
        for (int mt = 0; mt < 4; ++mt)
            #pragma unroll
            for (int r = 0; r < 4; ++r)
                densp[((size_t)blockIdx.z * n + i0 + wave * 64 + mt * 16 + q * 4 + r) * HEADS + head]
                    = accd[mt][r];
    }
}

// ============ normalize: out = sum_s outsp / sum_s densp ============
__global__ __launch_bounds__(256) void normalize(const float* __restrict__ outsp,
                                                 const float* __restrict__ densp,
                                                 float* __restrict__ out, int n, int splits) {
    const int g = blockIdx.x * 256 + threadIdx.x;
    const int i = g >> 6;
    const int c4 = (g & 63) * 4;
    const int head = c4 >> 6;
    float den = 0.f;
    for (int s = 0; s < splits; ++s) den += densp[((size_t)s * n + i) * HEADS + head];
    float4 v = {0.f, 0.f, 0.f, 0.f};
    for (int s = 0; s < splits; ++s) {
        const float4 t = *(const float4*)&outsp[(size_t)s * n * HD + (size_t)i * HD + c4];
        v.x += t.x; v.y += t.y; v.z += t.z; v.w += t.w;
    }
    const float inv = 1.0f / den;
    v.x *= inv; v.y *= inv; v.z *= inv; v.w *= inv;
    *(float4*)&out[(size_t)i * HD + c4] = v;
}

extern "C" void kernel_launch(void* const* d_in, const int* in_sizes, int n_in,
                              void* d_out, int out_size, void* d_ws, size_t ws_size,
                              hipStream_t stream) {
    const float* x   = (const float*)d_in[0];
    const int*   adj = (const int*)d_in[1];
    const float* W   = (const float*)d_in[2];
    const float* att = (const float*)d_in[3];
    float* out = (float*)d_out;

    const int in_dim = in_sizes[2] / HD;   // 256
    const int n = in_sizes[0] / in_dim;    // 4096

    char* ws = (char*)d_ws;
    size_t off = 0;
    auto alloc = [&](size_t bytes) -> void* {
        void* p = ws + off; off += (bytes + 255) & ~(size_t)255; return p;
    };
    __hip_bfloat16* xh = (__hip_bfloat16*)alloc((size_t)n * in_dim * 2);
    __hip_bfloat16* xl = (__hip_bfloat16*)alloc((size_t)n * in_dim * 2);
    __hip_bfloat16* wh = (__hip_bfloat16*)alloc((size_t)in_dim * HD * 2);
    __hip_bfloat16* wl = (__hip_bfloat16*)alloc((size_t)in_dim * HD * 2);
    float2* esrc = (float2*)alloc((size_t)HEADS * n * 8);
    float2* edst = (float2*)alloc((size_t)HEADS * n * 8);
    __hip_bfloat16* hbB = (__hip_bfloat16*)alloc((size_t)n * HD * 2);
    unsigned int* bits = (unsigned int*)alloc((size_t)n * (n / 8));

    const size_t outB = (size_t)n * HD * 4, denB = (size_t)n * HEADS * 4;
    float* densp = (float*)alloc((size_t)SPLITS * denB);
    float* outsp = (float*)alloc((size_t)SPLITS * outB);

    const int nxb = (n / 16) * (in_dim / 32) * 64 / 256;
    const int nwb = (HD / 16) * (in_dim / 32) * 64 / 256;
    pack_xw<<<nxb + nwb, 256, 0, stream>>>(x, W, xh, xl, wh, wl, in_dim, nxb);
    compress_adj<<<dim3(n / 1024, n), 256, 0, stream>>>(adj, bits, n);
    gemm_fused<<<dim3(n / 32, HEADS), 128, 0, stream>>>(xh, xl, wh, wl, att, esrc, edst, hbB, n, in_dim);
    aggregate<<<dim3(n / MI, HEADS, SPLITS), 256, 0, stream>>>(bits, esrc, edst, hbB, outsp, densp, n, n / SPLITS);
    normalize<<<n * 64 / 256, 256, 0, stream>>>(outsp, densp, out, n, SPLITS);
}